// Round 1
// baseline (534.970 us; speedup 1.0000x reference)
//
#include <hip/hip_runtime.h>

typedef __attribute__((ext_vector_type(8))) short short8;
typedef __attribute__((ext_vector_type(8))) unsigned short ushort8;
typedef __attribute__((ext_vector_type(4))) float f32x4;

static __device__ __forceinline__ unsigned short f2bf(float f) {
    union { float f; unsigned int u; } a; a.f = f;
    unsigned int u = a.u;
    return (unsigned short)((u + 0x7fffu + ((u >> 16) & 1u)) >> 16);  // RNE
}

// wt[b][rs][f][c] = bf16( kern[rs][c][f] * (style[b][c]+1) * rsqrt(sum_w2 + 1e-8) )
// f-major / c-contiguous so MFMA B-fragments are 16B-contiguous loads.
__global__ void prep_weights(const float* __restrict__ kern,
                             const float* __restrict__ style,
                             unsigned short* __restrict__ wt) {
    const int b = blockIdx.x;
    const int t = threadIdx.x;
    __shared__ float sty[128];
    __shared__ float demod[128];
    if (t < 128) sty[t] = style[b * 128 + t] + 1.0f;
    __syncthreads();
    if (t < 128) {
        const int f = t;
        float s = 0.0f;
        for (int rs = 0; rs < 9; ++rs)
            for (int c = 0; c < 128; ++c) {
                float w = kern[(rs * 128 + c) * 128 + f] * sty[c];
                s += w * w;
            }
        demod[f] = rsqrtf(s + 1e-8f);
    }
    __syncthreads();
    unsigned short* wb = wt + (size_t)b * (9 * 128 * 128);
    for (int i = t; i < 9 * 128 * 128; i += 256) {
        int c  = i & 127;
        int f  = (i >> 7) & 127;
        int rs = i >> 14;
        float w = kern[(rs * 128 + c) * 128 + f] * sty[c] * demod[f];
        wb[i] = f2bf(w);
    }
}

// One block = 8(h) x 16(w) spatial tile x all 128 F for one batch.
// M=128 (8 M-tiles of 16 = one w-row each), N=128 (8 F-tiles), K=9*128.
// Wave w: all 8 M-tiles x F-tiles {2w, 2w+1}. A from LDS halo, B direct from L2.
__global__ void mdconv(const float* __restrict__ x,
                       const unsigned short* __restrict__ wt,
                       float* __restrict__ out) {
    const int b   = blockIdx.z;
    const int h0  = blockIdx.y * 8;
    const int w0  = blockIdx.x * 16;
    const int tid = threadIdx.x;

    // halo: 10 rows x 18 cols x 128 ch bf16, pitch 136 (272B -> 4-bank rotate, 2-way max)
    __shared__ unsigned short xs[180 * 136];

    {
        const float* xb = x + (size_t)b * (128 * 128 * 128);
        for (int id = tid; id < 180 * 16; id += 256) {
            int p  = id >> 4;
            int cg = id & 15;
            int pr = p / 18;
            int pc = p - pr * 18;
            int hh = h0 - 1 + pr;
            int ww = w0 - 1 + pc;
            ushort8 v = {0, 0, 0, 0, 0, 0, 0, 0};
            if ((unsigned)hh < 128u && (unsigned)ww < 128u) {
                const float4* src =
                    (const float4*)(xb + ((size_t)(hh * 128 + ww) * 128 + cg * 8));
                float4 f0 = src[0];
                float4 f1 = src[1];
                v[0] = f2bf(f0.x); v[1] = f2bf(f0.y); v[2] = f2bf(f0.z); v[3] = f2bf(f0.w);
                v[4] = f2bf(f1.x); v[5] = f2bf(f1.y); v[6] = f2bf(f1.z); v[7] = f2bf(f1.w);
            }
            *(ushort8*)(xs + p * 136 + cg * 8) = v;
        }
    }
    __syncthreads();

    const int lane = tid & 63;
    const int wave = tid >> 6;
    const int fl   = lane & 15;        // A: m within M-tile / B: n within F-tile
    const int quad = lane >> 4;
    const int kq   = quad * 8;         // k sub-offset within a 32-wide k-step

    f32x4 acc[8][2];
    #pragma unroll
    for (int mt = 0; mt < 8; ++mt)
        #pragma unroll
        for (int j = 0; j < 2; ++j)
            acc[mt][j] = (f32x4){0.f, 0.f, 0.f, 0.f};

    // this wave's B base: b, f-tile pair (2*wave), n=fl, k=kq
    const unsigned short* wtb = wt + (size_t)b * (9 * 128 * 128)
                              + (size_t)wave * 4096 + fl * 128 + kq;

    #pragma unroll
    for (int rs = 0; rs < 9; ++rs) {
        const int r = rs / 3, s = rs % 3;
        #pragma unroll
        for (int kc = 0; kc < 4; ++kc) {
            const int k0 = kc * 32 + kq;
            short8 a[8];
            #pragma unroll
            for (int mt = 0; mt < 8; ++mt)
                a[mt] = *(const short8*)(xs + ((mt + r) * 18 + fl + s) * 136 + k0);
            #pragma unroll
            for (int j = 0; j < 2; ++j) {
                short8 bf = *(const short8*)(wtb + rs * 16384 + j * 2048 + kc * 32);
                #pragma unroll
                for (int mt = 0; mt < 8; ++mt)
                    acc[mt][j] =
                        __builtin_amdgcn_mfma_f32_16x16x32_bf16(a[mt], bf, acc[mt][j], 0, 0, 0);
            }
        }
    }

    // D layout: col = lane&15 (= f within tile), row = quad*4+reg (= w within M-tile)
    float* ob = out + ((size_t)(b * 128 + h0) * 128 + w0) * 128;
    #pragma unroll
    for (int mt = 0; mt < 8; ++mt) {
        #pragma unroll
        for (int j = 0; j < 2; ++j) {
            const int f = (wave * 2 + j) * 16 + fl;
            #pragma unroll
            for (int reg = 0; reg < 4; ++reg) {
                const int m = quad * 4 + reg;
                ob[((size_t)(mt * 128 + m)) * 128 + f] = acc[mt][j][reg];
            }
        }
    }
}

extern "C" void kernel_launch(void* const* d_in, const int* in_sizes, int n_in,
                              void* d_out, int out_size, void* d_ws, size_t ws_size,
                              hipStream_t stream) {
    const float* x     = (const float*)d_in[0];
    const float* style = (const float*)d_in[1];
    const float* kern  = (const float*)d_in[2];
    float* out = (float*)d_out;
    unsigned short* wt = (unsigned short*)d_ws;  // 8*9*128*128 bf16 = 2.36 MB

    prep_weights<<<dim3(8), dim3(256), 0, stream>>>(kern, style, wt);
    mdconv<<<dim3(8, 16, 8), dim3(256), 0, stream>>>(x, wt, out);
}

// Round 2
// 382.452 us; speedup vs baseline: 1.3988x; 1.3988x over previous
//
#include <hip/hip_runtime.h>

typedef __attribute__((ext_vector_type(8))) short short8;
typedef __attribute__((ext_vector_type(8))) unsigned short ushort8;
typedef __attribute__((ext_vector_type(4))) float f32x4;

static __device__ __forceinline__ unsigned short f2bf(float f) {
    union { float f; unsigned int u; } a; a.f = f;
    unsigned int u = a.u;
    return (unsigned short)((u + 0x7fffu + ((u >> 16) & 1u)) >> 16);  // RNE
}

// Stage 1: partial[b][rs][f] = sum_c (kern[rs][c][f] * (style[b][c]+1))^2
// Fully parallel (72 blocks), coalesced in f, 64 independent loads per thread.
__global__ void prep_sumsq(const float* __restrict__ kern,
                           const float* __restrict__ style,
                           float* __restrict__ partial) {
    const int rs = blockIdx.x;   // 0..8
    const int b  = blockIdx.y;   // 0..7
    const int t  = threadIdx.x;  // 256
    __shared__ float sty[128];
    __shared__ float red[256];
    if (t < 128) sty[t] = style[b * 128 + t] + 1.0f;
    __syncthreads();
    const int f = t & 127, half = t >> 7;
    const float* kp = kern + (size_t)rs * 16384 + f;
    float s = 0.0f;
    #pragma unroll 8
    for (int c = half * 64; c < half * 64 + 64; ++c) {
        float w = kp[(size_t)c * 128] * sty[c];
        s += w * w;
    }
    red[t] = s;
    __syncthreads();
    if (t < 128) partial[((size_t)b * 9 + rs) * 128 + t] = red[t] + red[t + 128];
}

// Stage 2: wt[b][rs][f][c] = bf16(kern[rs][c][f] * sty[c] * demod[f])
// LDS transpose so both the kern read (f-contig) and wt write (c-contig) coalesce.
__global__ void prep_wt(const float* __restrict__ kern,
                        const float* __restrict__ style,
                        const float* __restrict__ partial,
                        unsigned short* __restrict__ wt) {
    const int rs = blockIdx.x, b = blockIdx.y;
    const int t  = threadIdx.x;  // 256
    __shared__ float sty[128], dm[128];
    __shared__ float ts[32][132];
    if (t < 128) {
        sty[t] = style[b * 128 + t] + 1.0f;
    } else {
        const int f = t - 128;
        float s = 0.0f;
        #pragma unroll
        for (int r = 0; r < 9; ++r) s += partial[((size_t)b * 9 + r) * 128 + f];
        dm[f] = rsqrtf(s + 1e-8f);
    }
    __syncthreads();
    const float* kp = kern + (size_t)rs * 16384;
    unsigned short* wp = wt + ((size_t)b * 9 + rs) * 16384;
    for (int c0 = 0; c0 < 128; c0 += 32) {
        {   // load 32c x 128f chunk, coalesced in f
            const int fi = (t & 31) * 4;
            const int ci = t >> 5;  // 0..7
            #pragma unroll
            for (int k = 0; k < 4; ++k) {
                const float4 v = *(const float4*)(kp + (size_t)(c0 + ci + 8 * k) * 128 + fi);
                ts[ci + 8 * k][fi + 0] = v.x;
                ts[ci + 8 * k][fi + 1] = v.y;
                ts[ci + 8 * k][fi + 2] = v.z;
                ts[ci + 8 * k][fi + 3] = v.w;
            }
        }
        __syncthreads();
        {   // store, coalesced in c (4 c per lane, ushort4)
            const int cb = (t & 7) * 4;
            const int f2 = t >> 3;  // 0..31
            #pragma unroll
            for (int k = 0; k < 4; ++k) {
                const int f = f2 + 32 * k;
                ushort4 o;
                o.x = f2bf(ts[cb + 0][f] * sty[c0 + cb + 0] * dm[f]);
                o.y = f2bf(ts[cb + 1][f] * sty[c0 + cb + 1] * dm[f]);
                o.z = f2bf(ts[cb + 2][f] * sty[c0 + cb + 2] * dm[f]);
                o.w = f2bf(ts[cb + 3][f] * sty[c0 + cb + 3] * dm[f]);
                *(ushort4*)(wp + (size_t)f * 128 + c0 + cb) = o;
            }
        }
        __syncthreads();
    }
}

// One block = 8(h) x 16(w) spatial tile x all 128 F for one batch.
// XCD-pinning: 1-D grid, batch = blockIdx & 7 so each XCD (RR over linear WG id,
// m09) serves ONE batch -> its 288 KB weight slice stays L2-resident.
__global__ void mdconv(const float* __restrict__ x,
                       const unsigned short* __restrict__ wt,
                       float* __restrict__ out) {
    const int lin = blockIdx.x;
    const int b   = lin & 7;
    const int sp  = lin >> 3;        // 0..127 raster over spatial tiles
    const int h0  = (sp >> 3) * 8;   // 16 h-tiles
    const int w0  = (sp & 7) * 16;   // 8 w-tiles
    const int tid = threadIdx.x;

    // halo: 10 rows x 18 cols x 128 ch bf16; pitch 138 el = 276 B = 69 dwords
    // (odd dword stride -> near-uniform bank rotation; was 136 -> 4-bank lattice)
    __shared__ unsigned short xs[180 * 138];

    {
        const float* xb = x + (size_t)b * (128 * 128 * 128);
        for (int id = tid; id < 180 * 16; id += 256) {
            int p  = id >> 4;
            int cg = id & 15;
            int pr = p / 18;
            int pc = p - pr * 18;
            int hh = h0 - 1 + pr;
            int ww = w0 - 1 + pc;
            ushort8 v = {0, 0, 0, 0, 0, 0, 0, 0};
            if ((unsigned)hh < 128u && (unsigned)ww < 128u) {
                const float4* src =
                    (const float4*)(xb + ((size_t)(hh * 128 + ww) * 128 + cg * 8));
                float4 f0 = src[0];
                float4 f1 = src[1];
                v[0] = f2bf(f0.x); v[1] = f2bf(f0.y); v[2] = f2bf(f0.z); v[3] = f2bf(f0.w);
                v[4] = f2bf(f1.x); v[5] = f2bf(f1.y); v[6] = f2bf(f1.z); v[7] = f2bf(f1.w);
            }
            *(ushort8*)(xs + p * 138 + cg * 8) = v;
        }
    }
    __syncthreads();

    const int lane = tid & 63;
    const int wave = tid >> 6;
    const int fl   = lane & 15;
    const int quad = lane >> 4;
    const int kq   = quad * 8;

    f32x4 acc[8][2];
    #pragma unroll
    for (int mt = 0; mt < 8; ++mt)
        #pragma unroll
        for (int j = 0; j < 2; ++j)
            acc[mt][j] = (f32x4){0.f, 0.f, 0.f, 0.f};

    const unsigned short* wtb = wt + (size_t)b * (9 * 128 * 128)
                              + (size_t)wave * 4096 + fl * 128 + kq;

    #pragma unroll
    for (int rs = 0; rs < 9; ++rs) {
        const int r = rs / 3, s = rs % 3;
        #pragma unroll
        for (int kc = 0; kc < 4; ++kc) {
            const int k0 = kc * 32 + kq;
            short8 a[8];
            #pragma unroll
            for (int mt = 0; mt < 8; ++mt)
                a[mt] = *(const short8*)(xs + ((mt + r) * 18 + fl + s) * 138 + k0);
            #pragma unroll
            for (int j = 0; j < 2; ++j) {
                short8 bf = *(const short8*)(wtb + rs * 16384 + j * 2048 + kc * 32);
                #pragma unroll
                for (int mt = 0; mt < 8; ++mt)
                    acc[mt][j] =
                        __builtin_amdgcn_mfma_f32_16x16x32_bf16(a[mt], bf, acc[mt][j], 0, 0, 0);
            }
        }
    }

    float* ob = out + ((size_t)(b * 128 + h0) * 128 + w0) * 128;
    #pragma unroll
    for (int mt = 0; mt < 8; ++mt) {
        #pragma unroll
        for (int j = 0; j < 2; ++j) {
            const int f = (wave * 2 + j) * 16 + fl;
            #pragma unroll
            for (int reg = 0; reg < 4; ++reg) {
                const int m = quad * 4 + reg;
                ob[((size_t)(mt * 128 + m)) * 128 + f] = acc[mt][j][reg];
            }
        }
    }
}

extern "C" void kernel_launch(void* const* d_in, const int* in_sizes, int n_in,
                              void* d_out, int out_size, void* d_ws, size_t ws_size,
                              hipStream_t stream) {
    const float* x     = (const float*)d_in[0];
    const float* style = (const float*)d_in[1];
    const float* kern  = (const float*)d_in[2];
    float* out = (float*)d_out;

    unsigned short* wt = (unsigned short*)d_ws;                       // 2359296 B
    float* partial = (float*)((char*)d_ws + (size_t)8 * 9 * 128 * 128 * 2);  // 36864 B

    prep_sumsq<<<dim3(9, 8), dim3(256), 0, stream>>>(kern, style, partial);
    prep_wt<<<dim3(9, 8), dim3(256), 0, stream>>>(kern, style, partial, wt);
    mdconv<<<dim3(1024), dim3(256), 0, stream>>>(x, wt, out);
}

// Round 3
// 204.439 us; speedup vs baseline: 2.6168x; 1.8707x over previous
//
#include <hip/hip_runtime.h>

typedef __attribute__((ext_vector_type(8))) short short8;
typedef __attribute__((ext_vector_type(8))) unsigned short ushort8;
typedef __attribute__((ext_vector_type(4))) float f32x4;

static __device__ __forceinline__ unsigned short f2bf(float f) {
    union { float f; unsigned int u; } a; a.f = f;
    unsigned int u = a.u;
    return (unsigned short)((u + 0x7fffu + ((u >> 16) & 1u)) >> 16);  // RNE
}

// ---------------- prep: modulated+demodulated weights (bf16) ----------------
// Stage 1: partial[b][rs][f] = sum_c (kern[rs][c][f] * (style[b][c]+1))^2
__global__ void prep_sumsq(const float* __restrict__ kern,
                           const float* __restrict__ style,
                           float* __restrict__ partial) {
    const int rs = blockIdx.x;   // 0..8
    const int b  = blockIdx.y;   // 0..7
    const int t  = threadIdx.x;  // 256
    __shared__ float sty[128];
    __shared__ float red[256];
    if (t < 128) sty[t] = style[b * 128 + t] + 1.0f;
    __syncthreads();
    const int f = t & 127, half = t >> 7;
    const float* kp = kern + (size_t)rs * 16384 + f;
    float s = 0.0f;
    #pragma unroll 8
    for (int c = half * 64; c < half * 64 + 64; ++c) {
        float w = kp[(size_t)c * 128] * sty[c];
        s += w * w;
    }
    red[t] = s;
    __syncthreads();
    if (t < 128) partial[((size_t)b * 9 + rs) * 128 + t] = red[t] + red[t + 128];
}

// Stage 2: wt[b][rs][f][c] = bf16(kern[rs][c][f] * sty[c] * demod[f]), c-contig.
__global__ void prep_wt(const float* __restrict__ kern,
                        const float* __restrict__ style,
                        const float* __restrict__ partial,
                        unsigned short* __restrict__ wt) {
    const int rs = blockIdx.x, b = blockIdx.y;
    const int t  = threadIdx.x;  // 256
    __shared__ float sty[128], dm[128];
    __shared__ float ts[32][132];
    if (t < 128) {
        sty[t] = style[b * 128 + t] + 1.0f;
    } else {
        const int f = t - 128;
        float s = 0.0f;
        #pragma unroll
        for (int r = 0; r < 9; ++r) s += partial[((size_t)b * 9 + r) * 128 + f];
        dm[f] = rsqrtf(s + 1e-8f);
    }
    __syncthreads();
    const float* kp = kern + (size_t)rs * 16384;
    unsigned short* wp = wt + ((size_t)b * 9 + rs) * 16384;
    for (int c0 = 0; c0 < 128; c0 += 32) {
        {
            const int fi = (t & 31) * 4;
            const int ci = t >> 5;
            #pragma unroll
            for (int k = 0; k < 4; ++k) {
                const float4 v = *(const float4*)(kp + (size_t)(c0 + ci + 8 * k) * 128 + fi);
                ts[ci + 8 * k][fi + 0] = v.x;
                ts[ci + 8 * k][fi + 1] = v.y;
                ts[ci + 8 * k][fi + 2] = v.z;
                ts[ci + 8 * k][fi + 3] = v.w;
            }
        }
        __syncthreads();
        {
            const int cb = (t & 7) * 4;
            const int f2 = t >> 3;
            #pragma unroll
            for (int k = 0; k < 4; ++k) {
                const int f = f2 + 32 * k;
                ushort4 o;
                o.x = f2bf(ts[cb + 0][f] * sty[c0 + cb + 0] * dm[f]);
                o.y = f2bf(ts[cb + 1][f] * sty[c0 + cb + 1] * dm[f]);
                o.z = f2bf(ts[cb + 2][f] * sty[c0 + cb + 2] * dm[f]);
                o.w = f2bf(ts[cb + 3][f] * sty[c0 + cb + 3] * dm[f]);
                *(ushort4*)(wp + (size_t)f * 128 + c0 + cb) = o;
            }
        }
        __syncthreads();
    }
}

// ---------------- x -> padded bf16 NHWC [8][130][130][128] ----------------
// Zero border => main loop has NO bounds checks; A-frags load straight from global.
#define PROW 16640      // 130*128
#define PPLANE 2163200  // 130*PROW
__global__ void cvt_x(const float* __restrict__ x, unsigned short* __restrict__ xbf) {
    const int id = blockIdx.x * 256 + threadIdx.x;  // one ushort8 chunk
    if (id >= 8 * 130 * 130 * 16) return;
    const int cg = id & 15;
    const int p  = id >> 4;
    const int wp = p % 130;
    const int q  = p / 130;
    const int hp = q % 130;
    const int b  = q / 130;
    ushort8 v = {0, 0, 0, 0, 0, 0, 0, 0};
    if (hp >= 1 && hp <= 128 && wp >= 1 && wp <= 128) {
        const float4* src = (const float4*)(x + (((size_t)b * 128 + (hp - 1)) * 128 + (wp - 1)) * 128 + cg * 8);
        float4 f0 = src[0];
        float4 f1 = src[1];
        v[0] = f2bf(f0.x); v[1] = f2bf(f0.y); v[2] = f2bf(f0.z); v[3] = f2bf(f0.w);
        v[4] = f2bf(f1.x); v[5] = f2bf(f1.y); v[6] = f2bf(f1.z); v[7] = f2bf(f1.w);
    }
    *(ushort8*)(xbf + (size_t)p * 128 + cg * 8) = v;
}

// ---------------- main conv: weights LDS-resident, no main-loop barriers ----
// Block: 512 thr (8 waves), one batch, 64 F (fh half), 512 px = 4 h-rows x 128 w.
// Wave wv: h-row = wv>>1, w-half = (wv&1)*64, 4 M-tiles x 4 F-tiles, acc 64 regs.
// wt slice staged once to LDS (pitch 136 el: fl-stride 68 dw -> conflict-free b128).
__global__ __launch_bounds__(512) void mdconv2(const unsigned short* __restrict__ xbf,
                                               const unsigned short* __restrict__ wt,
                                               float* __restrict__ out) {
    const int lin = blockIdx.x;          // ((b*32+spg)*2+fh)
    const int fh  = lin & 1;
    const int spg = (lin >> 1) & 31;
    const int b   = lin >> 6;
    const int tid = threadIdx.x;

    __shared__ unsigned short wtl[9 * 64 * 136];  // 156,672 B

    {   // stage wt[b][rs][fh*64+f][0..128) -> wtl[(rs*64+f)*136 + c]
        for (int idx = tid; idx < 576 * 16; idx += 512) {
            const int row = idx >> 4;        // rs*64 + f
            const int c8  = idx & 15;
            const int rs  = row >> 6;
            const int f   = row & 63;
            const ushort8 v = *(const ushort8*)(wt + (((size_t)b * 9 + rs) * 128 + fh * 64 + f) * 128 + c8 * 8);
            *(ushort8*)(wtl + row * 136 + c8 * 8) = v;
        }
    }
    __syncthreads();  // the ONLY barrier

    const int lane = tid & 63;
    const int wv   = tid >> 6;
    const int fl   = lane & 15;
    const int quad = lane >> 4;
    const int kq   = quad * 8;

    const int hrow  = spg * 4 + (wv >> 1);   // output h
    const int wbase = (wv & 1) * 64;         // output w base

    f32x4 acc[4][4];
    #pragma unroll
    for (int mt = 0; mt < 4; ++mt)
        #pragma unroll
        for (int ft = 0; ft < 4; ++ft)
            acc[mt][ft] = (f32x4){0.f, 0.f, 0.f, 0.f};

    const unsigned short* xb = xbf + (size_t)b * PPLANE;

    #pragma unroll
    for (int rs = 0; rs < 9; ++rs) {
        const int r = rs / 3, s = rs % 3;
        // padded coords: hp = hrow + r, wp = wbase + mt*16 + fl + s
        const unsigned short* arow = xb + ((size_t)(hrow + r) * 130 + wbase + s) * 128 + fl * 128 + kq;
        const unsigned short* brow = wtl + (size_t)rs * (64 * 136) + fl * 136 + kq;
        #pragma unroll
        for (int kc = 0; kc < 4; ++kc) {
            short8 a[4];
            #pragma unroll
            for (int mt = 0; mt < 4; ++mt)
                a[mt] = *(const short8*)(arow + mt * 16 * 128 + kc * 32);
            short8 bf[4];
            #pragma unroll
            for (int ft = 0; ft < 4; ++ft)
                bf[ft] = *(const short8*)(brow + ft * 16 * 136 + kc * 32);
            #pragma unroll
            for (int mt = 0; mt < 4; ++mt)
                #pragma unroll
                for (int ft = 0; ft < 4; ++ft)
                    acc[mt][ft] =
                        __builtin_amdgcn_mfma_f32_16x16x32_bf16(a[mt], bf[ft], acc[mt][ft], 0, 0, 0);
        }
    }

    // D: col=lane&15 -> f-within-tile, row=quad*4+reg -> w-within-Mtile
    float* ob = out + ((size_t)(b * 128 + hrow) * 128) * 128;
    #pragma unroll
    for (int mt = 0; mt < 4; ++mt) {
        #pragma unroll
        for (int ft = 0; ft < 4; ++ft) {
            const int f = fh * 64 + ft * 16 + fl;
            #pragma unroll
            for (int reg = 0; reg < 4; ++reg) {
                const int w = wbase + mt * 16 + quad * 4 + reg;
                ob[(size_t)w * 128 + f] = acc[mt][ft][reg];
            }
        }
    }
}

// ---------------- R2 fallback (used only if ws too small) ----------------
__global__ void mdconv_fb(const float* __restrict__ x,
                          const unsigned short* __restrict__ wt,
                          float* __restrict__ out) {
    const int lin = blockIdx.x;
    const int b   = lin & 7;
    const int sp  = lin >> 3;
    const int h0  = (sp >> 3) * 8;
    const int w0  = (sp & 7) * 16;
    const int tid = threadIdx.x;
    __shared__ unsigned short xs[180 * 138];
    {
        const float* xb = x + (size_t)b * (128 * 128 * 128);
        for (int id = tid; id < 180 * 16; id += 256) {
            int p  = id >> 4;
            int cg = id & 15;
            int pr = p / 18;
            int pc = p - pr * 18;
            int hh = h0 - 1 + pr;
            int ww = w0 - 1 + pc;
            ushort8 v = {0, 0, 0, 0, 0, 0, 0, 0};
            if ((unsigned)hh < 128u && (unsigned)ww < 128u) {
                const float4* src = (const float4*)(xb + ((size_t)(hh * 128 + ww) * 128 + cg * 8));
                float4 f0 = src[0];
                float4 f1 = src[1];
                v[0] = f2bf(f0.x); v[1] = f2bf(f0.y); v[2] = f2bf(f0.z); v[3] = f2bf(f0.w);
                v[4] = f2bf(f1.x); v[5] = f2bf(f1.y); v[6] = f2bf(f1.z); v[7] = f2bf(f1.w);
            }
            *(ushort8*)(xs + p * 138 + cg * 8) = v;
        }
    }
    __syncthreads();
    const int lane = tid & 63;
    const int wave = tid >> 6;
    const int fl   = lane & 15;
    const int quad = lane >> 4;
    const int kq   = quad * 8;
    f32x4 acc[8][2];
    #pragma unroll
    for (int mt = 0; mt < 8; ++mt)
        #pragma unroll
        for (int j = 0; j < 2; ++j)
            acc[mt][j] = (f32x4){0.f, 0.f, 0.f, 0.f};
    const unsigned short* wtb = wt + (size_t)b * (9 * 128 * 128) + (size_t)wave * 4096 + fl * 128 + kq;
    #pragma unroll
    for (int rs = 0; rs < 9; ++rs) {
        const int r = rs / 3, s = rs % 3;
        #pragma unroll
        for (int kc = 0; kc < 4; ++kc) {
            const int k0 = kc * 32 + kq;
            short8 a[8];
            #pragma unroll
            for (int mt = 0; mt < 8; ++mt)
                a[mt] = *(const short8*)(xs + ((mt + r) * 18 + fl + s) * 138 + k0);
            #pragma unroll
            for (int j = 0; j < 2; ++j) {
                short8 bf = *(const short8*)(wtb + rs * 16384 + j * 2048 + kc * 32);
                #pragma unroll
                for (int mt = 0; mt < 8; ++mt)
                    acc[mt][j] = __builtin_amdgcn_mfma_f32_16x16x32_bf16(a[mt], bf, acc[mt][j], 0, 0, 0);
            }
        }
    }
    float* ob = out + ((size_t)(b * 128 + h0) * 128 + w0) * 128;
    #pragma unroll
    for (int mt = 0; mt < 8; ++mt)
        #pragma unroll
        for (int j = 0; j < 2; ++j) {
            const int f = (wave * 2 + j) * 16 + fl;
            #pragma unroll
            for (int reg = 0; reg < 4; ++reg)
                ob[((size_t)(mt * 128 + quad * 4 + reg)) * 128 + f] = acc[mt][j][reg];
        }
}

extern "C" void kernel_launch(void* const* d_in, const int* in_sizes, int n_in,
                              void* d_out, int out_size, void* d_ws, size_t ws_size,
                              hipStream_t stream) {
    const float* x     = (const float*)d_in[0];
    const float* style = (const float*)d_in[1];
    const float* kern  = (const float*)d_in[2];
    float* out = (float*)d_out;

    const size_t XBF_BYTES = (size_t)8 * 130 * 130 * 128 * 2;  // 34,611,200
    const size_t WT_BYTES  = (size_t)8 * 9 * 128 * 128 * 2;    //  2,359,296
    const size_t NEED      = XBF_BYTES + WT_BYTES + 36864;

    if (ws_size >= NEED) {
        unsigned short* xbf = (unsigned short*)d_ws;
        unsigned short* wt  = (unsigned short*)((char*)d_ws + XBF_BYTES);
        float* partial      = (float*)((char*)d_ws + XBF_BYTES + WT_BYTES);
        prep_sumsq<<<dim3(9, 8), dim3(256), 0, stream>>>(kern, style, partial);
        prep_wt<<<dim3(9, 8), dim3(256), 0, stream>>>(kern, style, partial, wt);
        cvt_x<<<dim3((8 * 130 * 130 * 16 + 255) / 256), dim3(256), 0, stream>>>(x, xbf);
        mdconv2<<<dim3(512), dim3(512), 0, stream>>>(xbf, wt, out);
    } else {
        unsigned short* wt = (unsigned short*)d_ws;
        float* partial     = (float*)((char*)d_ws + WT_BYTES);
        prep_sumsq<<<dim3(9, 8), dim3(256), 0, stream>>>(kern, style, partial);
        prep_wt<<<dim3(9, 8), dim3(256), 0, stream>>>(kern, style, partial, wt);
        mdconv_fb<<<dim3(1024), dim3(256), 0, stream>>>(x, wt, out);
    }
}